// Round 1
// baseline (298.494 us; speedup 1.0000x reference)
//
#include <hip/hip_runtime.h>
#include <hip/hip_fp16.h>

// VQ codebook quantization, MI355X.
//   prep:   fp32->bf16 fragment repack + norms + all zero-inits (no memsets).
//   passA:  bf16 MFMA 32x32x16, 1 M-frag (32 codes)/wave, 32-row B tiles in
//           LDS (2x16KB dbuf) -> ~115 VGPR, 4 blocks/CU (launch_bounds 256,4).
//   passB12: stream tm, per-row min+EPS ballot -> block-local pair list in LDS,
//            then waves rescore pairs exactly (fp32) + atomicMin64. (fused B1+B2)
//   passB34: wave per 8 rows: gather quantized, indices, counts, loss partials;
//            last block (ticket) reduces counts+loss -> perplexity/losses. (fused)
// B=8192, d_latent=512, ncb=2, K=8192, d_sub=256.

#define KCODES 8192
#define DSUB   256
#define BROWS  8192
#define NROWS  16384
#define NWIN   512

#define QUANT_N  (BROWS * 512)
#define IDX_OFF  QUANT_N
#define LOSS_OFF (QUANT_N + NROWS)

// ws layout (bytes)
#define WS_ESQ     0          // 16384 f32
#define WS_ZSQ     65536      // 16384 f32
#define WS_COUNTS  131072     // 16384 i32   (zeroed in prep)
#define WS_WINNER  196608     // 16384 u64   (0xFF.. in prep)
#define WS_LOSSARR 327680     // 2048 f32    (zeroed in prep, atomicAdd in B34)
#define WS_QTAIL   335872     // 1 u32       (zeroed in prep; ticket for B34)
#define WS_ZBF     1048576    // [2][8192][256] bf16 = 8 MB, fragment layout
#define WS_EBF     9437184    // [2][8192][256] bf16 = 8 MB, fragment layout
#define WS_TM      17825792   // [2][8192][512] fp16 = 16 MB

#define EPS 2.5e-4f

// Fragment layout (elements, per codebook): row r, element k ->
//   (r>>4)*4096 + (k>>5)*512 + ((k>>3)&3)*128 + (r&15)*8 + (k&7)
// 32x32x16 view: lane (l5,c32) reads short8 at
//   (grp + (c32>>4))*4096 + (k0>>1)*512 + (k0&1)*256 + l5*128 + (lane&15)*8.

typedef __attribute__((ext_vector_type(8))) short short8;
typedef __attribute__((ext_vector_type(8))) unsigned short ushort8v;
typedef __attribute__((ext_vector_type(16))) float floatx16;

__device__ inline void gl2lds16(const void* g, void* l) {
  __builtin_amdgcn_global_load_lds(
      (const __attribute__((address_space(1))) void*)g,
      (__attribute__((address_space(3))) void*)l, 16, 0, 0);
}

__device__ inline unsigned short f2bf(float f) {
  unsigned u = __float_as_uint(f);
  return (unsigned short)((u + 0x7FFFu + ((u >> 16) & 1u)) >> 16);
}

__device__ inline int agent_load_i(const int* p) {
  return __hip_atomic_load(p, __ATOMIC_RELAXED, __HIP_MEMORY_SCOPE_AGENT);
}
__device__ inline float agent_load_f(const float* p) {
  return __hip_atomic_load(p, __ATOMIC_RELAXED, __HIP_MEMORY_SCOPE_AGENT);
}

// ------------------------------------------------------------ prep kernel
__global__ void prep_kernel(const float* __restrict__ z, const float* __restrict__ e,
                            float* __restrict__ e_sq, float* __restrict__ z_sq,
                            unsigned short* __restrict__ zbf, unsigned short* __restrict__ ebf,
                            int* __restrict__ counts, unsigned long long* __restrict__ winner,
                            unsigned* __restrict__ qtail, float* __restrict__ lossarr) {
  int t = blockIdx.x * 256 + threadIdx.x;
  if (t < 16384) { counts[t] = 0; winner[t] = ~0ull; }
  if (t < 2048) lossarr[t] = 0.0f;
  if (t == 16384) *qtail = 0;

  int gw  = blockIdx.x * 4 + (threadIdx.x >> 6);  // 0..4095
  int l   = threadIdx.x & 63;
  int sub = l >> 5;
  int l32 = l & 31;
  for (int i = 0; i < 4; ++i) {
    int row = i * 8192 + gw * 2 + sub;            // 0..32767 (i<2: emb, else z)
    const float* src;
    unsigned short* dst;
    int r;
    float* sq;
    int sqi;
    if (row < NROWS) {
      src = e + (size_t)row * DSUB;
      dst = ebf; r = row; sq = e_sq; sqi = row;
    } else {
      int rz = row - NROWS;
      int n = rz & 1, b = rz >> 1;
      src = z + (size_t)rz * DSUB;
      dst = zbf + (size_t)n * 2097152; r = b; sq = z_sq; sqi = rz;
    }
    float4 v0 = ((const float4*)src)[2 * l32];
    float4 v1 = ((const float4*)src)[2 * l32 + 1];
    ushort8v o;
    o[0] = f2bf(v0.x); o[1] = f2bf(v0.y); o[2] = f2bf(v0.z); o[3] = f2bf(v0.w);
    o[4] = f2bf(v1.x); o[5] = f2bf(v1.y); o[6] = f2bf(v1.z); o[7] = f2bf(v1.w);
    size_t off = (size_t)(r >> 4) * 4096 + (l32 >> 2) * 512 + (l32 & 3) * 128 + (r & 15) * 8;
    *(ushort8v*)(dst + off) = o;
    float s = v0.x * v0.x + v0.y * v0.y + v0.z * v0.z + v0.w * v0.w
            + v1.x * v1.x + v1.y * v1.y + v1.z * v1.z + v1.w * v1.w;
    #pragma unroll
    for (int off2 = 16; off2; off2 >>= 1) s += __shfl_down(s, off2, 32);
    if (l32 == 0) sq[sqi] = s;
  }
}

// ------------------------------------------------------------ pass A (MFMA)
// Grid (64, 16, 2), 256 threads. Block = 128 codes x 512 rows (16 nt of 32).
// Wave w: 32 codes (1 M-frag); B 32-row tile in LDS (1 frag x 16 k), dbuf.
// ~115 VGPR incl. 16 AGPR acc -> 4 blocks/CU, 4 waves/SIMD.
__global__ __launch_bounds__(256, 4)
void passA_kernel(const unsigned short* __restrict__ zbf, const unsigned short* __restrict__ ebf,
                  const float* __restrict__ e_sq, __half* __restrict__ tm) {
  __shared__ unsigned short Bs[2][8192];          // 2 x 16KB

  const int n    = blockIdx.z;
  const int tid  = threadIdx.x;
  const int w    = tid >> 6, lane = tid & 63;
  const int l5   = lane >> 5, c32 = lane & 31;
  const int cb   = blockIdx.x * 128 + w * 32;
  const int rg   = blockIdx.y * 512;

  const unsigned short* en = ebf + (size_t)n * 2097152;
  const unsigned short* zn = zbf + (size_t)n * 2097152;
  const float* esq = e_sq + n * KCODES;
  __half* tmn = tm + (size_t)n * (BROWS * NWIN);

  // lane-constant fragment address part (elements)
  const int lo = (c32 >> 4) * 4096 + l5 * 128 + (lane & 15) * 8;

  // A fragments: 16 k-steps, short8 each (64 VGPR)
  short8 areg[16];
  #pragma unroll
  for (int k0 = 0; k0 < 16; ++k0)
    areg[k0] = *(const short8*)(en + (size_t)(cb >> 4) * 4096
                                + (k0 >> 1) * 512 + (k0 & 1) * 256 + lo);

  // e_sq per acc reg: code = cb + (reg&3) + 8*(reg>>2) + 4*l5
  float eq[16];
  #pragma unroll
  for (int reg = 0; reg < 16; ++reg)
    eq[reg] = esq[cb + (reg & 3) + 8 * (reg >> 2) + 4 * l5];

  // stage first 16KB B tile (4KB per wave)
  const unsigned short* zg = zn + (size_t)(rg >> 4) * 4096;
  {
    const int eo = w * 2048 + lane * 8;
    #pragma unroll
    for (int i = 0; i < 4; ++i)
      gl2lds16(zg + i * 512 + eo, &Bs[0][w * 2048 + i * 512]);
  }

  for (int nt = 0; nt < 16; ++nt) {
    __syncthreads();            // staged buffer ready; prev buffer readers done
    if (nt < 15) {
      const unsigned short* zs = zg + (nt + 1) * 8192;
      unsigned short* ld = &Bs[(nt + 1) & 1][0];
      const int eo = w * 2048 + lane * 8;
      #pragma unroll
      for (int i = 0; i < 4; ++i)
        gl2lds16(zs + i * 512 + eo, ld + w * 2048 + i * 512);
    }
    const unsigned short* bsrc = &Bs[nt & 1][0];
    const int rowbase = rg + nt * 32;

    floatx16 acc;
    #pragma unroll
    for (int i = 0; i < 16; ++i) acc[i] = 0.f;

    #pragma unroll
    for (int k0 = 0; k0 < 16; ++k0) {
      short8 b0 = *(const short8*)&bsrc[(k0 >> 1) * 512 + (k0 & 1) * 256 + lo];
      acc = __builtin_amdgcn_mfma_f32_32x32x16_bf16(areg[k0], b0, acc, 0, 0, 0);
    }

    // epilogue: window A = regs 0-7 (codes cb..cb+15), window B = regs 8-15.
    float pA = eq[0] - 2.0f * acc[0];
    float pB = eq[8] - 2.0f * acc[8];
    #pragma unroll
    for (int r = 1; r < 8; ++r) {
      pA = fminf(pA, eq[r] - 2.0f * acc[r]);
      pB = fminf(pB, eq[r + 8] - 2.0f * acc[r + 8]);
    }
    pA = fminf(pA, __shfl_xor(pA, 32, 64));
    pB = fminf(pB, __shfl_xor(pB, 32, 64));
    if (l5 == 0) {
      int zr = rowbase + c32;
      ushort2 o;
      o.x = __half_as_ushort(__float2half(pA));
      o.y = __half_as_ushort(__float2half(pB));
      *(ushort2*)&tmn[(size_t)zr * NWIN + (cb >> 4)] = o;
    }
  }
}

// ------------------------------------------------------------ passB12 (select+rescore)
// Phase 1 (per wave, 8 rows): per-row fp16 min + EPS ballot -> LDS pair list.
// Phase 2: waves grid-stride the block's pair list; exact fp32 rescore,
//          wave-reduce, atomicMin64 into winner. No global queue round-trip.
__global__ __launch_bounds__(256)
void passB12_kernel(const __half* __restrict__ tm, const float* __restrict__ z,
                    const float* __restrict__ emb, const float* __restrict__ e_sq,
                    const float* __restrict__ z_sq,
                    unsigned long long* __restrict__ winner) {
  __shared__ unsigned buf[4][512];
  __shared__ unsigned wcnt[4];
  __shared__ unsigned pre[5];

  const int w = threadIdx.x >> 6, lane = threadIdx.x & 63;
  const int gw = blockIdx.x * 4 + w;
  const int r0 = gw * 8;

  uint4 tq[8];
  #pragma unroll
  for (int i = 0; i < 8; ++i) {
    int row = r0 + i;
    int n = row & 1, b = row >> 1;
    tq[i] = *(const uint4*)(tm + ((size_t)n * BROWS + b) * NWIN + lane * 8);
  }

  unsigned cnt = 0;
  #pragma unroll
  for (int i = 0; i < 8; ++i) {
    int row = r0 + i;
    float t[8];
    __half2 h;
    h = *(__half2*)&tq[i].x; t[0] = __low2float(h); t[1] = __high2float(h);
    h = *(__half2*)&tq[i].y; t[2] = __low2float(h); t[3] = __high2float(h);
    h = *(__half2*)&tq[i].z; t[4] = __low2float(h); t[5] = __high2float(h);
    h = *(__half2*)&tq[i].w; t[6] = __low2float(h); t[7] = __high2float(h);
    float mv = t[0];
    #pragma unroll
    for (int j = 1; j < 8; ++j) mv = fminf(mv, t[j]);
    #pragma unroll
    for (int off = 32; off; off >>= 1) mv = fminf(mv, __shfl_xor(mv, off, 64));
    const float thr = mv + EPS;
    #pragma unroll
    for (int j = 0; j < 8; ++j) {
      unsigned long long mb = __ballot(t[j] <= thr);
      while (mb) {
        int src = __ffsll(mb) - 1;
        mb &= mb - 1;
        if (cnt < 512) {
          if (lane == 0) buf[w][cnt] = ((unsigned)row << 16) | (unsigned)(src * 8 + j);
          ++cnt;
        }
      }
    }
  }
  if (lane == 0) wcnt[w] = cnt;
  __syncthreads();
  if (threadIdx.x == 0) {
    unsigned s = 0;
    #pragma unroll
    for (int i = 0; i < 4; ++i) { pre[i] = s; s += wcnt[i]; }
    pre[4] = s;
  }
  __syncthreads();

  const unsigned total = pre[4];
  const int q = lane & 3, g = lane >> 2;
  for (unsigned idx = (unsigned)w; idx < total; idx += 4) {
    int bkt = 0;                                  // wave-uniform search (<=3 iters)
    while (bkt < 3 && idx >= pre[bkt + 1]) ++bkt;
    unsigned e = buf[bkt][idx - pre[bkt]];
    int row = e >> 16, win = e & 0xFFFF;
    int n = row & 1;
    int code = win * 16 + g;
    const float4* ep = (const float4*)(emb + ((size_t)n * KCODES + code) * DSUB);
    const float4* zp = (const float4*)(z + (size_t)row * DSUB);

    float s = 0.f;
    #pragma unroll
    for (int u = 0; u < 16; ++u) {
      float4 ev = ep[q + 4 * u];
      float4 zv = zp[q + 4 * u];
      s += ev.x * zv.x; s += ev.y * zv.y; s += ev.z * zv.z; s += ev.w * zv.w;
    }
    s += __shfl_xor(s, 1, 64);
    s += __shfl_xor(s, 2, 64);

    float bd = (z_sq[row] - 2.0f * s) + e_sq[n * KCODES + code];
    int   bk = code;
    #pragma unroll
    for (int off = 4; off < 64; off <<= 1) {
      float d2 = __shfl_xor(bd, off, 64);
      int   k2 = __shfl_xor(bk, off, 64);
      if (d2 < bd || (d2 == bd && k2 < bk)) { bd = d2; bk = k2; }
    }
    if (lane == 0)
      atomicMin(&winner[row], ((unsigned long long)__float_as_uint(bd) << 32) | (unsigned)bk);
  }
}

// ------------------------------------------------------------ passB34 (gather+final)
__global__ __launch_bounds__(256)
void passB34_kernel(const float* __restrict__ z, const float* __restrict__ emb,
                    const unsigned long long* __restrict__ winner, float* __restrict__ out,
                    int* __restrict__ counts, float* __restrict__ lossarr,
                    unsigned* __restrict__ ticket) {
  const int w = threadIdx.x >> 6, lane = threadIdx.x & 63;
  const int gw = blockIdx.x * 4 + w;        // 0..2047
  float lossacc = 0.f;

  for (int i = 0; i < 4; ++i) {
    int row0 = gw * 8 + i * 2;
    int bk0 = (int)(unsigned)winner[row0];
    int bk1 = (int)(unsigned)winner[row0 + 1];
    const float* eb0 = emb + ((size_t)(row0 & 1) * KCODES + bk0) * DSUB;
    const float* eb1 = emb + ((size_t)((row0 + 1) & 1) * KCODES + bk1) * DSUB;
    float4 ev0 = ((const float4*)eb0)[lane];
    float4 ev1 = ((const float4*)eb1)[lane];
    float4 zv0 = ((const float4*)(z + (size_t)row0 * DSUB))[lane];
    float4 zv1 = ((const float4*)(z + (size_t)(row0 + 1) * DSUB))[lane];
    ((float4*)(out + (size_t)row0 * DSUB))[lane] = ev0;
    ((float4*)(out + (size_t)(row0 + 1) * DSUB))[lane] = ev1;
    float dx = zv0.x - ev0.x, dy = zv0.y - ev0.y, dz = zv0.z - ev0.z, dw = zv0.w - ev0.w;
    lossacc += dx * dx + dy * dy + dz * dz + dw * dw;
    dx = zv1.x - ev1.x; dy = zv1.y - ev1.y; dz = zv1.z - ev1.z; dw = zv1.w - ev1.w;
    lossacc += dx * dx + dy * dy + dz * dz + dw * dw;
    if (lane == 0) {
      out[IDX_OFF + row0] = (float)bk0;
      out[IDX_OFF + row0 + 1] = (float)bk1;
      atomicAdd(&counts[(row0 & 1) * KCODES + bk0], 1);
      atomicAdd(&counts[((row0 + 1) & 1) * KCODES + bk1], 1);
    }
  }
  #pragma unroll
  for (int off = 32; off; off >>= 1) lossacc += __shfl_xor(lossacc, off, 64);
  if (lane == 0) atomicAdd(&lossarr[gw], lossacc);

  // ---- ticket: last block reduces counts + loss (fused final) ----
  __shared__ unsigned lastflag;
  __threadfence();
  __syncthreads();
  if (threadIdx.x == 0) lastflag = atomicAdd(ticket, 1);
  __syncthreads();
  if (lastflag != gridDim.x - 1) return;

  __shared__ float redh[256];
  __shared__ float redl[256];
  float h = 0.0f, ls = 0.0f;
  for (int k = threadIdx.x; k < KCODES; k += 256) {
    float c0 = (float)agent_load_i(&counts[k]);
    float c1 = (float)agent_load_i(&counts[KCODES + k]);
    float p = (c0 + c1) * (1.0f / 16384.0f);
    h -= p * logf(p + 1e-10f);
  }
  for (int k = threadIdx.x; k < 2048; k += 256) ls += agent_load_f(&lossarr[k]);
  redh[threadIdx.x] = h;
  redl[threadIdx.x] = ls;
  __syncthreads();
  for (int s = 128; s; s >>= 1) {
    if (threadIdx.x < s) {
      redh[threadIdx.x] += redh[threadIdx.x + s];
      redl[threadIdx.x] += redl[threadIdx.x + s];
    }
    __syncthreads();
  }
  if (threadIdx.x == 0) {
    out[LOSS_OFF + 0] = 0.25f * redl[0] * (1.0f / (float)QUANT_N);
    out[LOSS_OFF + 1] = 0.0f;
    out[LOSS_OFF + 2] = expf(redh[0]);
  }
}

extern "C" void kernel_launch(void* const* d_in, const int* in_sizes, int n_in,
                              void* d_out, int out_size, void* d_ws, size_t ws_size,
                              hipStream_t stream) {
  const float* z   = (const float*)d_in[0];
  const float* emb = (const float*)d_in[1];
  float* out = (float*)d_out;
  char*  ws  = (char*)d_ws;

  float* e_sq   = (float*)(ws + WS_ESQ);
  float* z_sq   = (float*)(ws + WS_ZSQ);
  int*   counts = (int*)(ws + WS_COUNTS);
  unsigned long long* winner = (unsigned long long*)(ws + WS_WINNER);
  float* lossarr = (float*)(ws + WS_LOSSARR);
  unsigned* qtail = (unsigned*)(ws + WS_QTAIL);
  unsigned short* zbf = (unsigned short*)(ws + WS_ZBF);
  unsigned short* ebf = (unsigned short*)(ws + WS_EBF);
  __half* tmbuf = (__half*)(ws + WS_TM);

  prep_kernel<<<1024, 256, 0, stream>>>(z, emb, e_sq, z_sq, zbf, ebf, counts, winner, qtail, lossarr);
  dim3 gA(64, 16, 2);
  passA_kernel<<<gA, 256, 0, stream>>>(zbf, ebf, e_sq, tmbuf);
  passB12_kernel<<<512, 256, 0, stream>>>(tmbuf, z, emb, e_sq, z_sq, winner);
  passB34_kernel<<<512, 256, 0, stream>>>(z, emb, winner, out, counts, lossarr, qtail);
}